// Round 8
// baseline (1138.331 us; speedup 1.0000x reference)
//
#include <hip/hip_runtime.h>
#include <hip/hip_fp16.h>

#define SEQ   512
#define BATCH 64
#define EMB   256
#define HID   512

// rnn W_hh split per row: 192 pairs (384 cols) in registers split across a
// thread PAIR (96 pairs each), 64 pairs (128 cols) in LDS split 32/32.
#define RC 96      // register pairs per thread
#define LCT 32     // LDS pairs per thread
#define WLROW 68   // pairs per LDS row (17 x 16B units; odd -> staggered banks)
#define SL1 36     // pair offset of half-1 slice within a row (unit 9: odd stagger)

typedef _Float16 half2v  __attribute__((ext_vector_type(2)));
typedef _Float16 half8v  __attribute__((ext_vector_type(8)));   // 16B ds_read_b128
typedef _Float16 half32v __attribute__((ext_vector_type(32)));  // 16 VGPRs, named

__device__ __forceinline__ float dot2acc(half2v a, half2v b, float c) {
#if defined(__has_builtin)
#if __has_builtin(__builtin_amdgcn_fdot2)
  return __builtin_amdgcn_fdot2(a, b, c, false);
#else
  return fmaf((float)a[0], (float)b[0], fmaf((float)a[1], (float)b[1], c));
#endif
#else
  return fmaf((float)a[0], (float)b[0], fmaf((float)a[1], (float)b[1], c));
#endif
}

__device__ __forceinline__ float fast_tanh(float x) {
  x = fminf(fmaxf(x, -15.f), 15.f);
  float e = __expf(2.f * x);
  return (e - 1.f) / (e + 1.f);
}

__device__ __forceinline__ half32v load32f(const float* p) {
  const float4* q = reinterpret_cast<const float4*>(p);
  float4 v0=q[0],v1=q[1],v2=q[2],v3=q[3],v4=q[4],v5=q[5],v6=q[6],v7=q[7];
  half32v r = {
    (_Float16)v0.x,(_Float16)v0.y,(_Float16)v0.z,(_Float16)v0.w,
    (_Float16)v1.x,(_Float16)v1.y,(_Float16)v1.z,(_Float16)v1.w,
    (_Float16)v2.x,(_Float16)v2.y,(_Float16)v2.z,(_Float16)v2.w,
    (_Float16)v3.x,(_Float16)v3.y,(_Float16)v3.z,(_Float16)v3.w,
    (_Float16)v4.x,(_Float16)v4.y,(_Float16)v4.z,(_Float16)v4.w,
    (_Float16)v5.x,(_Float16)v5.y,(_Float16)v5.z,(_Float16)v5.w,
    (_Float16)v6.x,(_Float16)v6.y,(_Float16)v6.z,(_Float16)v6.w,
    (_Float16)v7.x,(_Float16)v7.y,(_Float16)v7.z,(_Float16)v7.w };
  return r;
}

template<int M>
__device__ __forceinline__ void dot4(half32v wv, half8v hv,
                                     float& a0, float& a1, float& a2, float& a3) {
  a0 = dot2acc(__builtin_shufflevector(wv, wv, 8*M+0, 8*M+1),
               __builtin_shufflevector(hv, hv, 0, 1), a0);
  a1 = dot2acc(__builtin_shufflevector(wv, wv, 8*M+2, 8*M+3),
               __builtin_shufflevector(hv, hv, 2, 3), a1);
  a2 = dot2acc(__builtin_shufflevector(wv, wv, 8*M+4, 8*M+5),
               __builtin_shufflevector(hv, hv, 4, 5), a2);
  a3 = dot2acc(__builtin_shufflevector(wv, wv, 8*M+6, 8*M+7),
               __builtin_shufflevector(hv, hv, 6, 7), a3);
}

__device__ __forceinline__ void dot_chunk(half32v wv, const half8v* hp, int qb,
                                          float& a0, float& a1, float& a2, float& a3) {
  dot4<0>(wv, hp[qb + 0], a0, a1, a2, a3);
  dot4<1>(wv, hp[qb + 1], a0, a1, a2, a3);
  dot4<2>(wv, hp[qb + 2], a0, a1, a2, a3);
  dot4<3>(wv, hp[qb + 3], a0, a1, a2, a3);
}

// X[t][b][j] = dot(emb[text[t][b]], W_ih[j]) + b_ih[j] + b_hh[j], stored f16.
// (unchanged; ~150us, optimize after rnn is fixed)
__global__ __launch_bounds__(512) void proj_kernel(
    const int* __restrict__ text, const float* __restrict__ emb,
    const float* __restrict__ Wih, const float* __restrict__ bih,
    const float* __restrict__ bhh, __half* __restrict__ X) {
  __shared__ __align__(16) __half se[BATCH][EMB];  // 32 KB
  __shared__ int stok[BATCH];

  const int t = blockIdx.x;
  const int j = threadIdx.x;

  if (j < BATCH) stok[j] = text[t * BATCH + j];
  __syncthreads();

  {
    const int r = j >> 3;
    const int c0 = (j & 7) * 32;
    const float4* src = reinterpret_cast<const float4*>(emb + (size_t)stok[r] * EMB + c0);
    half2v* rowp = reinterpret_cast<half2v*>(&se[r][0]);
#pragma unroll
    for (int q = 0; q < 8; ++q) {
      float4 v = src[q];
      half2v p0; p0[0] = (_Float16)v.x; p0[1] = (_Float16)v.y;
      half2v p1; p1[0] = (_Float16)v.z; p1[1] = (_Float16)v.w;
      rowp[c0 / 2 + 2 * q + 0] = p0;
      rowp[c0 / 2 + 2 * q + 1] = p1;
    }
  }
  __syncthreads();

  float acc[BATCH];
#pragma unroll
  for (int b = 0; b < BATCH; ++b) acc[b] = 0.f;

  for (int ec = 0; ec < EMB / 32; ++ec) {
    half2v wh[16];
    const float4* wp = reinterpret_cast<const float4*>(Wih + (size_t)j * EMB + ec * 32);
#pragma unroll
    for (int q = 0; q < 8; ++q) {
      float4 v = wp[q];
      wh[2 * q + 0][0] = (_Float16)v.x; wh[2 * q + 0][1] = (_Float16)v.y;
      wh[2 * q + 1][0] = (_Float16)v.z; wh[2 * q + 1][1] = (_Float16)v.w;
    }
#pragma unroll
    for (int b = 0; b < BATCH; ++b) {
      const half8v* ep = reinterpret_cast<const half8v*>(&se[b][ec * 32]);  // broadcast
      float a = acc[b];
#pragma unroll
      for (int r = 0; r < 4; ++r) {
        half8v ev = ep[r];
        a = dot2acc(wh[4*r+0], __builtin_shufflevector(ev, ev, 0, 1), a);
        a = dot2acc(wh[4*r+1], __builtin_shufflevector(ev, ev, 2, 3), a);
        a = dot2acc(wh[4*r+2], __builtin_shufflevector(ev, ev, 4, 5), a);
        a = dot2acc(wh[4*r+3], __builtin_shufflevector(ev, ev, 6, 7), a);
      }
      acc[b] = a;
    }
  }

  const float bias = bih[j] + bhh[j];
#pragma unroll
  for (int b = 0; b < BATCH; ++b)
    X[((size_t)t * BATCH + b) * HID + j] = __float2half(acc[b] + bias);
}

// One block (1024 threads) per batch element. Thread pair (lanes 2r, 2r+1)
// owns hidden row r: half hf = tid&1 covers reg cols [hf*192, hf*192+192)
// (6 named half32v = 96 VGPRs) plus LDS cols [384+hf*64, +64). Partner
// partials combine via __shfl_xor(.,1) (same wave) -> still 1 barrier/step.
// Per-thread demand ~126 VGPRs: fits the empirical 128-VGPR cap that three
// attribute spellings (rounds 5-7) could not lift (all: VGPR=128, 21MB spill).
__global__ __launch_bounds__(1024) void rnn_kernel(
    const __half* __restrict__ X, const float* __restrict__ Whh,
    const float* __restrict__ Wfc, const float* __restrict__ bfc,
    float* __restrict__ out) {
  __shared__ __align__(16) half2v Wl[HID * WLROW];   // 136 KB
  __shared__ __align__(16) half2v h2[2][HID / 2];    // 2 KB
  __shared__ float red[32];

  const int tid = threadIdx.x;
  const int r   = tid >> 1;   // hidden row
  const int hf  = tid & 1;    // which half of the row
  const int b   = blockIdx.x;

  const float* wr = Whh + (size_t)r * HID;

  // stage LDS-resident W: row r global pairs [192+hf*32, 192+hf*32+32)
  // -> Wl[r][slice(hf)] with slice1 at pair SL1 (odd 16B-unit stagger)
  {
    const int dst0 = r * WLROW + (hf ? SL1 : 0);
#pragma unroll
    for (int c = 0; c < LCT; ++c) {
      float2 v = reinterpret_cast<const float2*>(wr)[192 + hf * LCT + c];
      half2v hh; hh[0] = (_Float16)v.x; hh[1] = (_Float16)v.y;
      Wl[dst0 + c] = hh;
    }
  }
  if (tid < HID / 2) {
    half2v z; z[0] = (_Float16)0.f; z[1] = (_Float16)0.f;
    h2[0][tid] = z;
  }
  __builtin_amdgcn_sched_barrier(0);

  // register-resident W: cols [hf*192, hf*192+192) as 6 named vectors,
  // sched_barrier between loads caps prologue register pressure
  const float* wb = wr + hf * 192;
  half32v w0 = load32f(wb +   0); __builtin_amdgcn_sched_barrier(0);
  half32v w1 = load32f(wb +  32); __builtin_amdgcn_sched_barrier(0);
  half32v w2 = load32f(wb +  64); __builtin_amdgcn_sched_barrier(0);
  half32v w3 = load32f(wb +  96); __builtin_amdgcn_sched_barrier(0);
  half32v w4 = load32f(wb + 128); __builtin_amdgcn_sched_barrier(0);
  half32v w5 = load32f(wb + 160); __builtin_amdgcn_sched_barrier(0);

  __syncthreads();

  const __half* Xp = X + (size_t)b * HID + r;  // stride per t = BATCH*HID
  float xv = __half2float(Xp[0]);
  float h = 0.f;
  int cur = 0;

  const int hq0 = hf * 24;        // reg-part h base (half8v units)
  const int hq1 = 48 + hf * 8;    // LDS-part h base
  const half8v* wl = reinterpret_cast<const half8v*>(&Wl[r * WLROW + (hf ? SL1 : 0)]);

  for (int t = 0; t < SEQ; ++t) {
    const int tn = (t < SEQ - 1) ? t + 1 : t;
    float xnext = __half2float(Xp[(size_t)tn * BATCH * HID]);

    const half8v* hp = reinterpret_cast<const half8v*>(&h2[cur][0]);

    float a0 = 0.f, a1 = 0.f, a2 = 0.f, a3 = 0.f;
    dot_chunk(w0, hp, hq0 +  0, a0, a1, a2, a3);
    dot_chunk(w1, hp, hq0 +  4, a0, a1, a2, a3);
    dot_chunk(w2, hp, hq0 +  8, a0, a1, a2, a3);
    dot_chunk(w3, hp, hq0 + 12, a0, a1, a2, a3);
    dot_chunk(w4, hp, hq0 + 16, a0, a1, a2, a3);
    dot_chunk(w5, hp, hq0 + 20, a0, a1, a2, a3);

#pragma unroll
    for (int q = 0; q < 8; ++q) {
      half8v hv = hp[hq1 + q];  // broadcast (2 addrs/wave: free)
      half8v wv = wl[q];        // per-lane b128, staggered banks
      a0 = dot2acc(__builtin_shufflevector(wv, wv, 0, 1),
                   __builtin_shufflevector(hv, hv, 0, 1), a0);
      a1 = dot2acc(__builtin_shufflevector(wv, wv, 2, 3),
                   __builtin_shufflevector(hv, hv, 2, 3), a1);
      a2 = dot2acc(__builtin_shufflevector(wv, wv, 4, 5),
                   __builtin_shufflevector(hv, hv, 4, 5), a2);
      a3 = dot2acc(__builtin_shufflevector(wv, wv, 6, 7),
                   __builtin_shufflevector(hv, hv, 6, 7), a3);
    }

    float part = ((a0 + a1) + (a2 + a3));
    part += __shfl_xor(part, 1, 64);   // combine with partner lane (same wave)
    h = fast_tanh(part + xv);
    xv = xnext;

    if (hf == 0) reinterpret_cast<__half*>(&h2[cur ^ 1][0])[r] = __float2half(h);
    __syncthreads();
    cur ^= 1;
  }

  // final FC: out[b][o] = sum_r W_fc[o][r]*h[r] + b_fc[o]
  float c0 = hf ? 0.f : Wfc[r] * h;
  float c1 = hf ? 0.f : Wfc[HID + r] * h;
#pragma unroll
  for (int o = 32; o > 0; o >>= 1) {
    c0 += __shfl_down(c0, o, 64);
    c1 += __shfl_down(c1, o, 64);
  }
  const int wave = tid >> 6;
  if ((tid & 63) == 0) { red[wave] = c0; red[16 + wave] = c1; }
  __syncthreads();
  if (tid == 0) {
    float s0 = 0.f, s1 = 0.f;
#pragma unroll
    for (int i = 0; i < 16; ++i) { s0 += red[i]; s1 += red[16 + i]; }
    out[b * 2 + 0] = s0 + bfc[0];
    out[b * 2 + 1] = s1 + bfc[1];
  }
}

extern "C" void kernel_launch(void* const* d_in, const int* in_sizes, int n_in,
                              void* d_out, int out_size, void* d_ws, size_t ws_size,
                              hipStream_t stream) {
  const int*   text = (const int*)d_in[0];
  const float* emb  = (const float*)d_in[1];
  const float* Wih  = (const float*)d_in[2];
  const float* Whh  = (const float*)d_in[3];
  const float* bih  = (const float*)d_in[4];
  const float* bhh  = (const float*)d_in[5];
  const float* Wfc  = (const float*)d_in[6];
  const float* bfc  = (const float*)d_in[7];
  float* outp = (float*)d_out;

  __half* X = (__half*)d_ws;  // SEQ*BATCH*HID f16 = 32 MiB

  proj_kernel<<<SEQ, 512, 0, stream>>>(text, emb, Wih, bih, bhh, X);
  rnn_kernel<<<BATCH, 1024, 0, stream>>>(X, Whh, Wfc, bfc, outp);
}